// Round 8
// baseline (284.894 us; speedup 1.0000x reference)
//
#include <hip/hip_runtime.h>
#include <hip/hip_bf16.h>

#define A_DIM 1024
#define B_DIM 16
#define DM    512
#define NH    8
#define HD    64
#define NTOK  (A_DIM * B_DIM)

#define LDT 72   // padded LDS leading dim (shorts) for the GEMM kernels
#define LOG2E 1.44269504088896f

typedef short s16x8 __attribute__((ext_vector_type(8)));   // 8 bf16, MFMA A/B frag
typedef short s16x4 __attribute__((ext_vector_type(4)));
typedef float f32x4 __attribute__((ext_vector_type(4)));   // MFMA C/D frag

static __device__ __forceinline__ unsigned short f2b(float f) {
    __hip_bfloat16 h = __float2bfloat16(f);
    unsigned short u;
    __builtin_memcpy(&u, &h, 2);
    return u;
}
static __device__ __forceinline__ float b2f(unsigned short u) {
    unsigned int w = ((unsigned int)u) << 16;
    float f;
    __builtin_memcpy(&f, &w, 4);
    return f;
}
// packed f32 pair -> bf16x2 in one uint (v_cvt_pk)
static __device__ __forceinline__ unsigned int pk2(float a, float b) {
    __hip_bfloat162 h = __float22bfloat162_rn(make_float2(a, b));
    unsigned int u;
    __builtin_memcpy(&u, &h, 4);
    return u;
}
static __device__ __forceinline__ uint2 cvt4(float4 v) {
    return make_uint2(pk2(v.x, v.y), pk2(v.z, v.w));
}

// ---------------------------------------------------------------------------
// Kernel 0: bias -> bf16, pre-scaled by log2e (softmax uses raw exp2).
// ---------------------------------------------------------------------------
__global__ __launch_bounds__(256) void bias_scale(
    const float* __restrict__ in, short* __restrict__ out)
{
    int i = (blockIdx.x * 256 + threadIdx.x) * 4;
    float4 v = *(const float4*)&in[i];
    uint2 u = cvt4(make_float4(v.x * LOG2E, v.y * LOG2E, v.z * LOG2E, v.w * LOG2E));
    *(uint2*)&out[i] = u;
}

// ---------------------------------------------------------------------------
// Kernel 1: fused QKV projection (unchanged from R6).  Q pre-scaled by
// HD^-0.5 * log2e.  Q,K,V -> [B][NH][A][HD] bf16.
// ---------------------------------------------------------------------------
__global__ __launch_bounds__(256) void qkv_gemm(
    const float* __restrict__ src,
    const float* __restrict__ Wq, const float* __restrict__ bq,
    const float* __restrict__ Wk, const float* __restrict__ bk,
    const float* __restrict__ Wv, const float* __restrict__ bv,
    short* __restrict__ Qb, short* __restrict__ Kb, short* __restrict__ Vb)
{
    __shared__ short As[128 * LDT];
    __shared__ short Bs[128 * LDT];

    const int tid  = threadIdx.x;
    const int wave = tid >> 6, lane = tid & 63;
    const int quad = lane >> 4, l16 = lane & 15;
    const int waveM = (wave >> 1) * 64, waveN = (wave & 1) * 64;
    const int mbase = blockIdx.y * 128;
    const int nbase = blockIdx.x * 128;          // 0..1535
    const int mat   = nbase >> 9;                // 0:Q 1:K 2:V
    const float* W    = (mat == 0) ? Wq : (mat == 1) ? Wk : Wv;
    const float* bvec = (mat == 0) ? bq : (mat == 1) ? bk : bv;
    short* dst        = (mat == 0) ? Qb : (mat == 1) ? Kb : Vb;
    const float oscale = (mat == 0) ? 0.125f * LOG2E : 1.0f;
    const int wrow0 = nbase & 511;

    f32x4 acc[4][4];
    #pragma unroll
    for (int i = 0; i < 4; i++)
        #pragma unroll
        for (int j = 0; j < 4; j++)
            acc[i][j] = (f32x4){0.f, 0.f, 0.f, 0.f};

    for (int kb = 0; kb < 8; ++kb) {
        __syncthreads();
        #pragma unroll
        for (int p = 0; p < 8; p++) {
            int chunk = tid + p * 256;
            int row = chunk >> 4, c = chunk & 15;
            float4 a4 = *(const float4*)&src[(mbase + row) * 512 + kb * 64 + c * 4];
            *(uint2*)&As[row * LDT + c * 4] = cvt4(a4);
            float4 w4 = *(const float4*)&W[(wrow0 + row) * 512 + kb * 64 + c * 4];
            *(uint2*)&Bs[row * LDT + c * 4] = cvt4(w4);
        }
        __syncthreads();
        #pragma unroll
        for (int k0i = 0; k0i < 2; k0i++) {
            s16x8 af[4], bf[4];
            #pragma unroll
            for (int mi = 0; mi < 4; mi++)
                af[mi] = *(const s16x8*)&As[(waveM + mi * 16 + l16) * LDT + (k0i * 4 + quad) * 8];
            #pragma unroll
            for (int ni = 0; ni < 4; ni++)
                bf[ni] = *(const s16x8*)&Bs[(waveN + ni * 16 + l16) * LDT + (k0i * 4 + quad) * 8];
            #pragma unroll
            for (int mi = 0; mi < 4; mi++)
                #pragma unroll
                for (int ni = 0; ni < 4; ni++)
                    acc[mi][ni] = __builtin_amdgcn_mfma_f32_16x16x32_bf16(
                        af[mi], bf[ni], acc[mi][ni], 0, 0, 0);
        }
    }

    #pragma unroll
    for (int mi = 0; mi < 4; mi++) {
        #pragma unroll
        for (int ni = 0; ni < 4; ni++) {
            #pragma unroll
            for (int r = 0; r < 4; r++) {
                int t = mbase + waveM + mi * 16 + quad * 4 + r;       // token = a*16+b
                int o = wrow0 + waveN + ni * 16 + l16;                // col in [0,512)
                float v = (acc[mi][ni][r] + bvec[o]) * oscale;
                int a = t >> 4, bb = t & 15, n = o >> 6, d = o & 63;
                dst[((bb * NH + n) * A_DIM + a) * HD + d] = (short)f2b(v);
            }
        }
    }
}

// ---------------------------------------------------------------------------
// Kernel 1b: in-place rewrite of V into PV-fragment order, per 64x64 tile.
// Tile (bn,kb) occupies the same contiguous 8 KB in both layouts.
// Output: tile = 8 sets (s = db*2+pr) x 64 lanes x 8 shorts, where piece
// (s,lane=(quad,l16)) = [V^T[d][pr*32+quad*4+0..3], V^T[d][pr*32+16+quad*4+0..3]],
// d = db*16+l16  -- exactly the B-fragment the attention PV mfma consumes.
// ---------------------------------------------------------------------------
__global__ __launch_bounds__(256) void v_transpose(short* __restrict__ V)
{
    __shared__ short Lt[64 * LDT];   // Lt[k][d]

    const int tid = threadIdx.x;
    short* T = V + ((size_t)blockIdx.y * (A_DIM * HD)) + blockIdx.x * 64 * HD;

    #pragma unroll
    for (int p = 0; p < 2; p++) {
        int chunk = tid + p * 256;
        int row = chunk >> 3, c = chunk & 7;
        *(s16x8*)&Lt[row * LDT + c * 8] = *(const s16x8*)&T[row * 64 + c * 8];
    }
    __syncthreads();

    #pragma unroll
    for (int p = 0; p < 2; p++) {
        int id = tid + p * 256;            // 512 pieces
        int s = id >> 6, lane = id & 63;
        int quad = lane >> 4, l16 = lane & 15;
        int db = s >> 1, pr = s & 1;
        int d = db * 16 + l16;
        int k0 = pr * 32 + quad * 4;
        s16x8 o;
        #pragma unroll
        for (int i = 0; i < 4; i++) o[i]     = Lt[(k0 + i) * LDT + d];
        #pragma unroll
        for (int i = 0; i < 4; i++) o[4 + i] = Lt[(k0 + 16 + i) * LDT + d];
        *(s16x8*)&T[(s * 64 + lane) * 8] = o;
    }
}

// ---------------------------------------------------------------------------
// Kernel 2: flash attention, fragment-major LDS.  One wg per (b*nh, 64 q).
// S^T = K*Q^T (P stays in registers); LDS tiles stored in MFMA-fragment
// order -> all LDS accesses are linear ds_read/write_b128, conflict-free.
// Double-buffered with register prefetch; one barrier per k-tile.
// ---------------------------------------------------------------------------
__global__ __launch_bounds__(256) void attn_kernel(
    const short* __restrict__ Qb, const short* __restrict__ Kb,
    const short* __restrict__ Vt, const short* __restrict__ bias16,
    short* __restrict__ AO)
{
    __shared__ short KsF[2][8 * 512];   // 8 sets x 64 lanes x 8 shorts
    __shared__ short VsF[2][8 * 512];

    const int tid  = threadIdx.x;
    const int wave = tid >> 6, lane = tid & 63;
    const int quad = lane >> 4, l16 = lane & 15;
    const int bn = blockIdx.y;
    const int qrow0 = blockIdx.x * 64 + wave * 16;

    const short* Qg = Qb + (size_t)bn * (A_DIM * HD);
    const short* Kg = Kb + (size_t)bn * (A_DIM * HD);
    const short* Vg = Vt + (size_t)bn * (A_DIM * HD);
    const short* brow = bias16 + (size_t)(qrow0 + l16) * A_DIM;

    // Q fragments (B-operand): B[n=q=l16][k=k0i*32+quad*8+j]
    s16x8 qf[2];
    #pragma unroll
    for (int k0i = 0; k0i < 2; k0i++)
        qf[k0i] = *(const s16x8*)&Qg[(qrow0 + l16) * HD + k0i * 32 + quad * 8];

    // staging: wave w stages K sets {2w,2w+1} (cb=w, k0i=0/1) and V sets {2w,2w+1}
    const short* kga = Kg + (wave * 16 + l16) * HD + quad * 8;  // +32 for k0i=1
    const short* vga = Vg + wave * 1024 + lane * 8;             // +512 for 2nd set
    const int sk = wave * 2;

    float lsum = 0.f;
    f32x4 of[4];
    #pragma unroll
    for (int db = 0; db < 4; db++) of[db] = (f32x4){0.f, 0.f, 0.f, 0.f};

    // preload tile 0 into buffer 0
    {
        s16x8 k0 = *(const s16x8*)(kga);
        s16x8 k1 = *(const s16x8*)(kga + 32);
        s16x8 v0 = *(const s16x8*)(vga);
        s16x8 v1 = *(const s16x8*)(vga + 512);
        *(s16x8*)&KsF[0][(sk + 0) * 512 + lane * 8] = k0;
        *(s16x8*)&KsF[0][(sk + 1) * 512 + lane * 8] = k1;
        *(s16x8*)&VsF[0][(sk + 0) * 512 + lane * 8] = v0;
        *(s16x8*)&VsF[0][(sk + 1) * 512 + lane * 8] = v1;
    }

    for (int kb = 0; kb < 16; ++kb) {
        const int buf = kb & 1;
        __syncthreads();   // tile kb staged by all waves; prev compute done

        // prefetch next tile into registers (global latency overlaps compute)
        s16x8 kp0, kp1, vp0, vp1;
        if (kb < 15) {
            const short* kn = kga + (kb + 1) * 4096;
            const short* vn = vga + (kb + 1) * 4096;
            kp0 = *(const s16x8*)(kn);
            kp1 = *(const s16x8*)(kn + 32);
            vp0 = *(const s16x8*)(vn);
            vp1 = *(const s16x8*)(vn + 512);
        }

        // S^T = K Q^T : D[m=key=quad*4+r][n=q=l16], tiles cb=0..3
        float pv[4][4];
        #pragma unroll
        for (int cb = 0; cb < 4; cb++) {
            f32x4 st = (f32x4){0.f, 0.f, 0.f, 0.f};
            #pragma unroll
            for (int k0i = 0; k0i < 2; k0i++) {
                s16x8 kf = *(const s16x8*)&KsF[buf][(cb * 2 + k0i) * 512 + lane * 8];
                st = __builtin_amdgcn_mfma_f32_16x16x32_bf16(kf, qf[k0i], st, 0, 0, 0);
            }
            s16x4 bz = *(const s16x4*)&brow[kb * 64 + cb * 16 + quad * 4];
            #pragma unroll
            for (int r = 0; r < 4; r++) {
                float p = __builtin_exp2f(st[r] + b2f((unsigned short)bz[r]));
                pv[cb][r] = p;
                lsum += p;
            }
        }

        // P fragments in registers: A[m=q=l16][k-slot quad*8+j],
        // slot j -> key (j>>2)*16 + quad*4 + (j&3)  (pfA: keys 0..31, pfB: 32..63)
        uint4 ua = make_uint4(pk2(pv[0][0], pv[0][1]), pk2(pv[0][2], pv[0][3]),
                              pk2(pv[1][0], pv[1][1]), pk2(pv[1][2], pv[1][3]));
        uint4 ub = make_uint4(pk2(pv[2][0], pv[2][1]), pk2(pv[2][2], pv[2][3]),
                              pk2(pv[3][0], pv[3][1]), pk2(pv[3][2], pv[3][3]));
        s16x8 pfA, pfB;
        __builtin_memcpy(&pfA, &ua, 16);
        __builtin_memcpy(&pfB, &ub, 16);

        // O += P V : V fragments pre-permuted to the same key order
        #pragma unroll
        for (int db = 0; db < 4; db++) {
            s16x8 v0 = *(const s16x8*)&VsF[buf][(db * 2 + 0) * 512 + lane * 8];
            of[db] = __builtin_amdgcn_mfma_f32_16x16x32_bf16(pfA, v0, of[db], 0, 0, 0);
            s16x8 v1 = *(const s16x8*)&VsF[buf][(db * 2 + 1) * 512 + lane * 8];
            of[db] = __builtin_amdgcn_mfma_f32_16x16x32_bf16(pfB, v1, of[db], 0, 0, 0);
        }

        // stage prefetched tile into the other buffer
        if (kb < 15) {
            const int nb = buf ^ 1;
            *(s16x8*)&KsF[nb][(sk + 0) * 512 + lane * 8] = kp0;
            *(s16x8*)&KsF[nb][(sk + 1) * 512 + lane * 8] = kp1;
            *(s16x8*)&VsF[nb][(sk + 0) * 512 + lane * 8] = vp0;
            *(s16x8*)&VsF[nb][(sk + 1) * 512 + lane * 8] = vp1;
        }
    }

    // row-sums: lane holds partial for q=l16; reduce across quads
    lsum += __shfl_xor(lsum, 16);
    lsum += __shfl_xor(lsum, 32);
    float linv[4];
    #pragma unroll
    for (int r = 0; r < 4; r++)
        linv[r] = 1.0f / __shfl(lsum, (lane & 48) | (quad * 4 + r));

    // epilogue: of C-layout col=l16 -> d=db*16+l16, row=quad*4+r -> q
    const int b = bn >> 3, n = bn & 7;
    #pragma unroll
    for (int db = 0; db < 4; db++) {
        #pragma unroll
        for (int r = 0; r < 4; r++) {
            int a = qrow0 + quad * 4 + r;
            int d = db * 16 + l16;
            AO[((size_t)a * B_DIM + b) * DM + n * HD + d] = (short)f2b(of[db][r] * linv[r]);
        }
    }
}

// ---------------------------------------------------------------------------
// Kernel 3: output projection (unchanged from R6).
// ---------------------------------------------------------------------------
__global__ __launch_bounds__(256) void out_gemm(
    const short* __restrict__ Xin,
    const float* __restrict__ Wo, const float* __restrict__ bo,
    float* __restrict__ out)
{
    __shared__ short As[128 * LDT];
    __shared__ short Bs[128 * LDT];

    const int tid  = threadIdx.x;
    const int wave = tid >> 6, lane = tid & 63;
    const int quad = lane >> 4, l16 = lane & 15;
    const int waveM = (wave >> 1) * 64, waveN = (wave & 1) * 64;
    const int mbase = blockIdx.y * 128;
    const int nbase = blockIdx.x * 128;   // 0..511

    f32x4 acc[4][4];
    #pragma unroll
    for (int i = 0; i < 4; i++)
        #pragma unroll
        for (int j = 0; j < 4; j++)
            acc[i][j] = (f32x4){0.f, 0.f, 0.f, 0.f};

    for (int kb = 0; kb < 8; ++kb) {
        __syncthreads();
        #pragma unroll
        for (int p = 0; p < 4; p++) {
            int chunk = tid + p * 256;
            int row = chunk >> 3, c = chunk & 7;
            *(s16x8*)&As[row * LDT + c * 8] =
                *(const s16x8*)&Xin[(mbase + row) * 512 + kb * 64 + c * 8];
        }
        #pragma unroll
        for (int p = 0; p < 8; p++) {
            int chunk = tid + p * 256;
            int row = chunk >> 4, c = chunk & 15;
            float4 w4 = *(const float4*)&Wo[(nbase + row) * 512 + kb * 64 + c * 4];
            *(uint2*)&Bs[row * LDT + c * 4] = cvt4(w4);
        }
        __syncthreads();
        #pragma unroll
        for (int k0i = 0; k0i < 2; k0i++) {
            s16x8 af[4], bf[4];
            #pragma unroll
            for (int mi = 0; mi < 4; mi++)
                af[mi] = *(const s16x8*)&As[(waveM + mi * 16 + l16) * LDT + (k0i * 4 + quad) * 8];
            #pragma unroll
            for (int ni = 0; ni < 4; ni++)
                bf[ni] = *(const s16x8*)&Bs[(waveN + ni * 16 + l16) * LDT + (k0i * 4 + quad) * 8];
            #pragma unroll
            for (int mi = 0; mi < 4; mi++)
                #pragma unroll
                for (int ni = 0; ni < 4; ni++)
                    acc[mi][ni] = __builtin_amdgcn_mfma_f32_16x16x32_bf16(
                        af[mi], bf[ni], acc[mi][ni], 0, 0, 0);
        }
    }

    #pragma unroll
    for (int mi = 0; mi < 4; mi++) {
        #pragma unroll
        for (int ni = 0; ni < 4; ni++) {
            #pragma unroll
            for (int r = 0; r < 4; r++) {
                int t = mbase + waveM + mi * 16 + quad * 4 + r;
                int o = nbase + waveN + ni * 16 + l16;
                out[t * 512 + o] = acc[mi][ni][r] + bo[o];
            }
        }
    }
}

// ---------------------------------------------------------------------------
extern "C" void kernel_launch(void* const* d_in, const int* in_sizes, int n_in,
                              void* d_out, int out_size, void* d_ws, size_t ws_size,
                              hipStream_t stream) {
    const float* src  = (const float*)d_in[0];
    const float* bias = (const float*)d_in[1];
    const float* Wq   = (const float*)d_in[2];
    const float* bq   = (const float*)d_in[3];
    const float* Wk   = (const float*)d_in[4];
    const float* bk   = (const float*)d_in[5];
    const float* Wv   = (const float*)d_in[6];
    const float* bv   = (const float*)d_in[7];
    const float* Wo   = (const float*)d_in[8];
    const float* bo   = (const float*)d_in[9];

    short* ws = (short*)d_ws;
    short* Qb = ws;                        // 16 MB (Q pre-scaled by 0.125*log2e)
    short* Kb = ws + (size_t)(1 << 23);    // 16 MB
    short* Vb = ws + (size_t)(2 << 23);    // 16 MB; transposed in-place to frag order

    const bool big_ws = ws_size >= (size_t)(72u << 20);
    short* AO;
    short* bias16;
    if (big_ws) {
        AO     = ws + (size_t)3 * (1 << 23);                     // 16 MB @ 48
        bias16 = ws + (size_t)4 * (1 << 23);                     // 2 MB @ 64
    } else {
        AO     = (short*)d_out;                                  // [0,16 MB)
        bias16 = (short*)d_out + (size_t)(1 << 23);              // [16,18 MB)
    }

    bias_scale<<<dim3(1024), 256, 0, stream>>>(bias, bias16);
    qkv_gemm<<<dim3(12, 128), 256, 0, stream>>>(src, Wq, bq, Wk, bk, Wv, bv, Qb, Kb, Vb);
    v_transpose<<<dim3(16, 128), 256, 0, stream>>>(Vb);
    attn_kernel<<<dim3(16, 128), 256, 0, stream>>>(Qb, Kb, Vb, bias16, AO);

    if (big_ws) {
        out_gemm<<<dim3(4, 128), 256, 0, stream>>>(AO, Wo, bo, (float*)d_out);
    } else {
        float* Cs = (float*)d_ws;          // over dead Qb+Kb (32 MB)
        out_gemm<<<dim3(4, 128), 256, 0, stream>>>(AO, Wo, bo, Cs);
        (void)hipMemcpyAsync(d_out, Cs, (size_t)out_size * sizeof(float),
                             hipMemcpyDeviceToDevice, stream);
    }
}